// Round 4
// baseline (202.096 us; speedup 1.0000x reference)
//
#include <hip/hip_runtime.h>

#define DIM 1024
#define SEQ 2048
#define NH 16
#define HD 64
#define M_TOT 4096  // B*SEQ

typedef unsigned short u16;
typedef unsigned int u32;
typedef __attribute__((ext_vector_type(8))) short bf16x8;   // MFMA A/B operand
typedef __attribute__((ext_vector_type(4))) float f32x4;    // MFMA accumulator / f32 loads
typedef __attribute__((ext_vector_type(4))) u32 u32x4;      // 16B mover
typedef __attribute__((ext_vector_type(4))) u16 u16x4;      // 8B bf16 store

__device__ __forceinline__ u16 f2bf(float f) {
  u32 x = __builtin_bit_cast(u32, f);
  x = x + 0x7fffu + ((x >> 16) & 1u);  // RNE
  return (u16)(x >> 16);
}
__device__ __forceinline__ void gload_lds16(const void* g, void* l) {
  __builtin_amdgcn_global_load_lds(
      (const __attribute__((address_space(1))) u32*)g,
      (__attribute__((address_space(3))) u32*)l, 16, 0, 0);
}

__global__ __launch_bounds__(256)
void zero_out_k(u32* __restrict__ o, int n)
{
  int i = blockIdx.x * 256 + threadIdx.x;
  if (i < n) o[i] = 0;
}

// ------------------------------------------------------------ transpose
// W [K=1024][N=1024] f32 -> Wt [N][K] bf16, 4 matrices (z).
__global__ __launch_bounds__(256)
void transpose_weights(const float* __restrict__ w0, const float* __restrict__ w1,
                       const float* __restrict__ w2, const float* __restrict__ w3,
                       u16* __restrict__ wt)
{
  __shared__ u16 tile[64][72];  // +8 pad
  int z = blockIdx.z;
  const float* W = z == 0 ? w0 : z == 1 ? w1 : z == 2 ? w2 : w3;
  u16* Wt = wt + (size_t)z * DIM * DIM;
  int k0 = blockIdx.x * 64, n0 = blockIdx.y * 64;
  int t = threadIdx.x;
#pragma unroll
  for (int it = 0; it < 4; ++it) {
    int idx = it * 256 + t;          // [0,1024): 64 rows x 16 chunks of 4
    int lr = idx >> 4, c0 = (idx & 15) * 4;
    f32x4 v = *(const f32x4*)&W[(size_t)(k0 + lr) * DIM + n0 + c0];
    u16x4 h;
#pragma unroll
    for (int j = 0; j < 4; ++j) h[j] = f2bf(v[j]);
    *(u16x4*)&tile[lr][c0] = h;
  }
  __syncthreads();
#pragma unroll
  for (int it = 0; it < 2; ++it) {
    int idx = it * 256 + t;          // [0,512): 64 rows x 8 chunks of 8
    int nr = idx >> 3, c0 = (idx & 7) * 8;
    alignas(16) u16 tmp[8];
#pragma unroll
    for (int j = 0; j < 8; ++j) tmp[j] = tile[c0 + j][nr];
    *(u32x4*)&Wt[(size_t)(n0 + nr) * DIM + k0 + c0] = *(u32x4*)tmp;
  }
}

// ------------------------------------------------------------ GEMM (m97 structure)
// Y[M,N] = X[M,K] @ Wt[N,K]^T + bias. AF32: X is f32 (convert while staging);
// else X bf16 via global_load_lds. OUTF32: write f32; else bf16.
#define BM 128
#define BN 128
#define BK 32

template <bool AF32, bool OUTF32>
__device__ __forceinline__ void gemm_tile(
    const void* __restrict__ Xv, const u16* __restrict__ Wt,
    const float* __restrict__ bias, void* __restrict__ Yv,
    int bm, int bn)
{
  __shared__ u16 lA[BM * BK];
  __shared__ u16 lB[BN * BK];
  int t = threadIdx.x;
  int lane = t & 63, w = t >> 6;
  int wr = (w >> 1) * 64, wc = (w & 1) * 64;
  int rl = lane & 15, kb = (lane >> 4) * 8;

  f32x4 acc[4][4] = {};

  for (int k0 = 0; k0 < DIM; k0 += BK) {
    if (AF32) {
      const float* Xf = (const float*)Xv;
#pragma unroll
      for (int it = 0; it < 4; ++it) {
        int idx = it * 256 + t;        // [0,1024): 128 rows x 8 chunks of 4
        int row = idx >> 3, c4 = (idx & 7) * 4;
        f32x4 v = *(const f32x4*)&Xf[(size_t)(bm + row) * DIM + k0 + c4];
        u16x4 h;
#pragma unroll
        for (int j = 0; j < 4; ++j) h[j] = f2bf(v[j]);
        *(u16x4*)&lA[row * BK + c4] = h;
      }
    } else {
      const u16* Xh = (const u16*)Xv;
#pragma unroll
      for (int r = 0; r < 2; ++r) {
        int idx = r * 256 + t;         // [0,512): 128 rows x 4 chunks of 8
        int row = idx >> 2, ce = (idx & 3) * 8;
        gload_lds16(Xh + (size_t)(bm + row) * DIM + k0 + ce, (char*)lA + idx * 16);
      }
    }
#pragma unroll
    for (int r = 0; r < 2; ++r) {
      int idx = r * 256 + t;
      int row = idx >> 2, ce = (idx & 3) * 8;
      gload_lds16(Wt + (size_t)(bn + row) * DIM + k0 + ce, (char*)lB + idx * 16);
    }
    __syncthreads();
    bf16x8 a[4], b[4];
#pragma unroll
    for (int m = 0; m < 4; ++m)
      a[m] = *(const bf16x8*)&lA[(wr + m * 16 + rl) * BK + kb];
#pragma unroll
    for (int n = 0; n < 4; ++n)
      b[n] = *(const bf16x8*)&lB[(wc + n * 16 + rl) * BK + kb];
#pragma unroll
    for (int m = 0; m < 4; ++m)
#pragma unroll
      for (int n = 0; n < 4; ++n)
        acc[m][n] = __builtin_amdgcn_mfma_f32_16x16x32_bf16(a[m], b[n], acc[m][n], 0, 0, 0);
    __syncthreads();
  }

  int rh = (lane >> 4) * 4;
#pragma unroll
  for (int n = 0; n < 4; ++n) {
    int col = bn + wc + n * 16 + rl;
    float bv = bias[col];
#pragma unroll
    for (int m = 0; m < 4; ++m) {
      int row = bm + wr + m * 16 + rh;
#pragma unroll
      for (int r = 0; r < 4; ++r) {
        if (OUTF32)
          ((float*)Yv)[(size_t)(row + r) * DIM + col] = acc[m][n][r] + bv;
        else
          ((u16*)Yv)[(size_t)(row + r) * DIM + col] = f2bf(acc[m][n][r] + bv);
      }
    }
  }
}

__global__ __launch_bounds__(256)
void gemm_qkv(const float* __restrict__ xq, const float* __restrict__ xk, const float* __restrict__ xv,
              const u16* __restrict__ wt,
              const float* __restrict__ bq, const float* __restrict__ bk, const float* __restrict__ bv,
              u16* __restrict__ outbase)
{
  int z = blockIdx.z;
  const float* X = z == 0 ? xq : z == 1 ? xk : xv;
  const u16* Wt = wt + (size_t)z * DIM * DIM;
  const float* bias = z == 0 ? bq : z == 1 ? bk : bv;
  u16* Y = outbase + (size_t)z * M_TOT * DIM;
  gemm_tile<true, false>(X, Wt, bias, Y, blockIdx.x * BM, blockIdx.y * BN);
}

__global__ __launch_bounds__(256)
void gemm_o(const u16* __restrict__ X, const u16* __restrict__ Wt,
            const float* __restrict__ bias, float* __restrict__ Y)
{
  gemm_tile<false, true>(X, Wt, bias, Y, blockIdx.x * BM, blockIdx.y * BN);
}

// ------------------------------------------------------------ attention
// Padded LDS tiles (row stride 72 u16 = 144 B: 16B-aligned, 2-way alias free).
// grid (S/64, B*H), 4 waves; wave w owns q rows q0+16w..+15.
// O written in-place over Q (each block touches only its own rows x head).
__global__ __launch_bounds__(256)
void attn_fwd(const u16* Qp, const u16* __restrict__ Kp,
              const u16* __restrict__ Vp, u16* O)
{
  __shared__ u16 lK[64][72];    // K[kv][d]
  __shared__ u16 lVt[64][72];   // V^T[d][kv]
  __shared__ u16 lP[4][16][72]; // per-wave P[q][kv]

  int bh = blockIdx.y;
  int b = bh >> 4, h = bh & 15;
  int q0 = blockIdx.x * 64;
  int t = threadIdx.x, lane = t & 63, w = t >> 6;
  int q0w = q0 + w * 16;
  int rl = lane & 15, hi = lane >> 4;

  const u16* Qb = Qp + ((size_t)b * SEQ) * DIM + h * HD;
  const u16* Kb = Kp + ((size_t)b * SEQ) * DIM + h * HD;
  const u16* Vb = Vp + ((size_t)b * SEQ) * DIM + h * HD;

  bf16x8 qf0, qf1;
  {
    const u16* qrow = Qb + (size_t)(q0w + rl) * DIM + hi * 8;
    qf0 = *(const bf16x8*)qrow;
    qf1 = *(const bf16x8*)(qrow + 32);
  }

  f32x4 oacc[4] = {};
  float mrow[4], lrow[4];
#pragma unroll
  for (int r = 0; r < 4; ++r) { mrow[r] = -1e30f; lrow[r] = 0.f; }

  int ntiles = blockIdx.x + 1;
  for (int tile = 0; tile < ntiles; ++tile) {
    int kv0 = tile * 64;
    // ---- stage K [64][64] reg->padded LDS
#pragma unroll
    for (int i = 0; i < 2; ++i) {
      int linear = i * 256 + t;                 // [0,512)
      int row = linear >> 3, c8 = (linear & 7) * 8;
      bf16x8 kk8 = *(const bf16x8*)(Kb + (size_t)(kv0 + row) * DIM + c8);
      *(bf16x8*)&lK[row][c8] = kk8;
    }
    // ---- stage V transposed: lVt[d][kv]
#pragma unroll
    for (int i = 0; i < 2; ++i) {
      int kv = t & 63;
      int d0 = (t >> 6) * 8 + i * 32;
      bf16x8 vv = *(const bf16x8*)(Vb + (size_t)(kv0 + kv) * DIM + d0);
#pragma unroll
      for (int j = 0; j < 8; ++j) lVt[d0 + j][kv] = (u16)vv[j];
    }
    __syncthreads();

    if (kv0 <= q0w + 15) {
      // ---- QK^T: S[q=hi*4+r][kv=g*16+rl]
      float s[4][4];
#pragma unroll
      for (int g = 0; g < 4; ++g) {
        f32x4 c = {};
#pragma unroll
        for (int half = 0; half < 2; ++half) {
          int kvr = g * 16 + rl;
          bf16x8 kf = *(const bf16x8*)&lK[kvr][half * 32 + hi * 8];
          c = __builtin_amdgcn_mfma_f32_16x16x32_bf16(half ? qf1 : qf0, kf, c, 0, 0, 0);
        }
#pragma unroll
        for (int r = 0; r < 4; ++r) s[g][r] = c[r] * 0.125f;  // HD^-0.5
      }
      if (kv0 + 63 > q0w) {  // diagonal tile: causal mask
#pragma unroll
        for (int g = 0; g < 4; ++g) {
          int kv_abs = kv0 + g * 16 + rl;
#pragma unroll
          for (int r = 0; r < 4; ++r)
            if (kv_abs > q0w + hi * 4 + r) s[g][r] = -1e30f;
        }
      }
      // ---- online softmax (row q = hi*4+r spans 16 lanes rl=0..15)
      float pm[4];
#pragma unroll
      for (int r = 0; r < 4; ++r)
        pm[r] = fmaxf(fmaxf(s[0][r], s[1][r]), fmaxf(s[2][r], s[3][r]));
#pragma unroll
      for (int mm = 1; mm <= 8; mm <<= 1)
#pragma unroll
        for (int r = 0; r < 4; ++r)
          pm[r] = fmaxf(pm[r], __shfl_xor(pm[r], mm));
      float fac[4], psum[4], p[4][4];
#pragma unroll
      for (int r = 0; r < 4; ++r) {
        float mn = fmaxf(mrow[r], pm[r]);
        fac[r] = __expf(mrow[r] - mn);
        mrow[r] = mn;
        psum[r] = 0.f;
      }
#pragma unroll
      for (int g = 0; g < 4; ++g)
#pragma unroll
        for (int r = 0; r < 4; ++r) {
          p[g][r] = __expf(s[g][r] - mrow[r]);
          psum[r] += p[g][r];
        }
#pragma unroll
      for (int mm = 1; mm <= 8; mm <<= 1)
#pragma unroll
        for (int r = 0; r < 4; ++r)
          psum[r] += __shfl_xor(psum[r], mm);
#pragma unroll
      for (int r = 0; r < 4; ++r) {
        lrow[r] = lrow[r] * fac[r] + psum[r];
#pragma unroll
        for (int n = 0; n < 4; ++n) oacc[n][r] *= fac[r];
      }
      // ---- P -> padded LDS [q][kv] (per-wave buffer)
#pragma unroll
      for (int g = 0; g < 4; ++g)
#pragma unroll
        for (int r = 0; r < 4; ++r)
          lP[w][hi * 4 + r][g * 16 + rl] = f2bf(p[g][r]);
      // ---- PV: oacc[q][d] += P[q][kv] @ V[kv][d]
#pragma unroll
      for (int kk = 0; kk < 2; ++kk) {
        bf16x8 pf = *(const bf16x8*)&lP[w][rl][kk * 32 + hi * 8];
#pragma unroll
        for (int n = 0; n < 4; ++n) {
          bf16x8 vf = *(const bf16x8*)&lVt[n * 16 + rl][kk * 32 + hi * 8];
          oacc[n] = __builtin_amdgcn_mfma_f32_16x16x32_bf16(pf, vf, oacc[n], 0, 0, 0);
        }
      }
    }
    __syncthreads();
  }

#pragma unroll
  for (int n = 0; n < 4; ++n) {
    int d = n * 16 + rl;
#pragma unroll
    for (int r = 0; r < 4; ++r) {
      int q = q0w + hi * 4 + r;
      O[((size_t)b * SEQ + q) * DIM + h * HD + d] = f2bf(oacc[n][r] / lrow[r]);
    }
  }
}

// ------------------------------------------------------------ launch
extern "C" void kernel_launch(void* const* d_in, const int* in_sizes, int n_in,
                              void* d_out, int out_size, void* d_ws, size_t ws_size,
                              hipStream_t stream)
{
  (void)in_sizes; (void)n_in;
  const size_t MB = 1024ull * 1024ull;
  if (ws_size < 32 * MB) {  // diagnostic fallback
    zero_out_k<<<(out_size + 255) / 256, 256, 0, stream>>>((u32*)d_out, out_size);
    return;
  }

  u16* Wt = (u16*)d_ws;                               // 8 MB (4 transposed weights)
  u16* Qp = (u16*)((char*)d_ws + 8 * MB);             // 8 MB (also attention output)
  u16* Kp = (u16*)((char*)d_ws + 16 * MB);            // 8 MB
  u16* Vp = (u16*)((char*)d_ws + 24 * MB);            // 8 MB

  transpose_weights<<<dim3(16, 16, 4), 256, 0, stream>>>(
      (const float*)d_in[3], (const float*)d_in[5], (const float*)d_in[7],
      (const float*)d_in[9], Wt);
  gemm_qkv<<<dim3(32, 8, 3), 256, 0, stream>>>(
      (const float*)d_in[0], (const float*)d_in[1], (const float*)d_in[2], Wt,
      (const float*)d_in[4], (const float*)d_in[6], (const float*)d_in[8], Qp);
  attn_fwd<<<dim3(32, 32), 256, 0, stream>>>(Qp, Kp, Vp, Qp);
  gemm_o<<<dim3(32, 8), 256, 0, stream>>>(Qp, Wt + 3ll * DIM * DIM,
                                          (const float*)d_in[10], (float*)d_out);
}

// Round 5
// 154.338 us; speedup vs baseline: 1.3094x; 1.3094x over previous
//
#include <hip/hip_runtime.h>

#define DIM 1024
#define SEQ 2048
#define NH 16
#define HD 64
#define M_TOT 4096  // B*SEQ

typedef unsigned short u16;
typedef unsigned int u32;
typedef __attribute__((ext_vector_type(8))) short bf16x8;   // MFMA A/B operand
typedef __attribute__((ext_vector_type(4))) float f32x4;    // MFMA accumulator / f32 loads
typedef __attribute__((ext_vector_type(4))) u32 u32x4;      // 16B mover
typedef __attribute__((ext_vector_type(4))) u16 u16x4;      // 8B bf16 store

__device__ __forceinline__ u16 f2bf(float f) {
  u32 x = __builtin_bit_cast(u32, f);
  x = x + 0x7fffu + ((x >> 16) & 1u);  // RNE
  return (u16)(x >> 16);
}
__device__ __forceinline__ void gload_lds16(const void* g, void* l) {
  __builtin_amdgcn_global_load_lds(
      (const __attribute__((address_space(1))) u32*)g,
      (__attribute__((address_space(3))) u32*)l, 16, 0, 0);
}

__global__ __launch_bounds__(256)
void zero_out_k(u32* __restrict__ o, int n)
{
  int i = blockIdx.x * 256 + threadIdx.x;
  if (i < n) o[i] = 0;
}

// ------------------------------------------------------------ transpose
// W [K=1024][N=1024] f32 -> Wt [N][K] bf16, 4 matrices (z).
__global__ __launch_bounds__(256)
void transpose_weights(const float* __restrict__ w0, const float* __restrict__ w1,
                       const float* __restrict__ w2, const float* __restrict__ w3,
                       u16* __restrict__ wt)
{
  __shared__ u16 tile[64][72];  // +8 pad
  int z = blockIdx.z;
  const float* W = z == 0 ? w0 : z == 1 ? w1 : z == 2 ? w2 : w3;
  u16* Wt = wt + (size_t)z * DIM * DIM;
  int k0 = blockIdx.x * 64, n0 = blockIdx.y * 64;
  int t = threadIdx.x;
#pragma unroll
  for (int it = 0; it < 4; ++it) {
    int idx = it * 256 + t;          // [0,1024): 64 rows x 16 chunks of 4
    int lr = idx >> 4, c0 = (idx & 15) * 4;
    f32x4 v = *(const f32x4*)&W[(size_t)(k0 + lr) * DIM + n0 + c0];
    u16x4 h;
#pragma unroll
    for (int j = 0; j < 4; ++j) h[j] = f2bf(v[j]);
    *(u16x4*)&tile[lr][c0] = h;
  }
  __syncthreads();
#pragma unroll
  for (int it = 0; it < 2; ++it) {
    int idx = it * 256 + t;          // [0,512): 64 rows x 8 chunks of 8
    int nr = idx >> 3, c0 = (idx & 7) * 8;
    alignas(16) u16 tmp[8];
#pragma unroll
    for (int j = 0; j < 8; ++j) tmp[j] = tile[c0 + j][nr];
    *(u32x4*)&Wt[(size_t)(n0 + nr) * DIM + k0 + c0] = *(u32x4*)tmp;
  }
}

// ------------------------------------------------------------ GEMM (m97 structure)
#define BM 128
#define BN 128
#define BK 32

template <bool AF32, bool OUTF32>
__device__ __forceinline__ void gemm_tile(
    const void* __restrict__ Xv, const u16* __restrict__ Wt,
    const float* __restrict__ bias, void* __restrict__ Yv,
    int bm, int bn)
{
  __shared__ u16 lA[BM * BK];
  __shared__ u16 lB[BN * BK];
  int t = threadIdx.x;
  int lane = t & 63, w = t >> 6;
  int wr = (w >> 1) * 64, wc = (w & 1) * 64;
  int rl = lane & 15, kb = (lane >> 4) * 8;

  f32x4 acc[4][4] = {};

  for (int k0 = 0; k0 < DIM; k0 += BK) {
    if (AF32) {
      const float* Xf = (const float*)Xv;
#pragma unroll
      for (int it = 0; it < 4; ++it) {
        int idx = it * 256 + t;        // [0,1024): 128 rows x 8 chunks of 4
        int row = idx >> 3, c4 = (idx & 7) * 4;
        f32x4 v = *(const f32x4*)&Xf[(size_t)(bm + row) * DIM + k0 + c4];
        u16x4 h;
#pragma unroll
        for (int j = 0; j < 4; ++j) h[j] = f2bf(v[j]);
        *(u16x4*)&lA[row * BK + c4] = h;
      }
    } else {
      const u16* Xh = (const u16*)Xv;
#pragma unroll
      for (int r = 0; r < 2; ++r) {
        int idx = r * 256 + t;         // [0,512): 128 rows x 4 chunks of 8
        int row = idx >> 2, ce = (idx & 3) * 8;
        gload_lds16(Xh + (size_t)(bm + row) * DIM + k0 + ce, (char*)lA + idx * 16);
      }
    }
#pragma unroll
    for (int r = 0; r < 2; ++r) {
      int idx = r * 256 + t;
      int row = idx >> 2, ce = (idx & 3) * 8;
      gload_lds16(Wt + (size_t)(bn + row) * DIM + k0 + ce, (char*)lB + idx * 16);
    }
    __syncthreads();
    bf16x8 a[4], b[4];
#pragma unroll
    for (int m = 0; m < 4; ++m)
      a[m] = *(const bf16x8*)&lA[(wr + m * 16 + rl) * BK + kb];
#pragma unroll
    for (int n = 0; n < 4; ++n)
      b[n] = *(const bf16x8*)&lB[(wc + n * 16 + rl) * BK + kb];
#pragma unroll
    for (int m = 0; m < 4; ++m)
#pragma unroll
      for (int n = 0; n < 4; ++n)
        acc[m][n] = __builtin_amdgcn_mfma_f32_16x16x32_bf16(a[m], b[n], acc[m][n], 0, 0, 0);
    __syncthreads();
  }

  int rh = (lane >> 4) * 4;
#pragma unroll
  for (int n = 0; n < 4; ++n) {
    int col = bn + wc + n * 16 + rl;
    float bv = bias[col];
#pragma unroll
    for (int m = 0; m < 4; ++m) {
      int row = bm + wr + m * 16 + rh;
#pragma unroll
      for (int r = 0; r < 4; ++r) {
        if (OUTF32)
          ((float*)Yv)[(size_t)(row + r) * DIM + col] = acc[m][n][r] + bv;
        else
          ((u16*)Yv)[(size_t)(row + r) * DIM + col] = f2bf(acc[m][n][r] + bv);
      }
    }
  }
}

__global__ __launch_bounds__(256)
void gemm_qkv(const float* __restrict__ xq, const float* __restrict__ xk, const float* __restrict__ xv,
              const u16* __restrict__ wt,
              const float* __restrict__ bq, const float* __restrict__ bk, const float* __restrict__ bv,
              u16* __restrict__ outbase)
{
  int z = blockIdx.z;
  const float* X = z == 0 ? xq : z == 1 ? xk : xv;
  const u16* Wt = wt + (size_t)z * DIM * DIM;
  const float* bias = z == 0 ? bq : z == 1 ? bk : bv;
  u16* Y = outbase + (size_t)z * M_TOT * DIM;
  gemm_tile<true, false>(X, Wt, bias, Y, blockIdx.x * BM, blockIdx.y * BN);
}

__global__ __launch_bounds__(256)
void gemm_o(const u16* __restrict__ X, const u16* __restrict__ Wt,
            const float* __restrict__ bias, float* __restrict__ Y)
{
  gemm_tile<false, true>(X, Wt, bias, Y, blockIdx.x * BM, blockIdx.y * BN);
}

// ------------------------------------------------------------ attention
// One KV-tile worth of flash-attention update for one wave's 16 q-rows.
__device__ __forceinline__ void attn_compute(
    const u16 (*lK)[72], const u16 (*lVt)[72], u16 (*lPw)[72],
    bf16x8 qf0, bf16x8 qf1, int rl, int hi, int kv0, int qw, bool diag,
    f32x4* oacc, float* mrow, float* lrow)
{
  // QK^T: S[q=hi*4+r][kv=g*16+rl]
  float s[4][4];
#pragma unroll
  for (int g = 0; g < 4; ++g) {
    int kvr = g * 16 + rl;
    f32x4 c = {};
    c = __builtin_amdgcn_mfma_f32_16x16x32_bf16(qf0, *(const bf16x8*)&lK[kvr][hi * 8], c, 0, 0, 0);
    c = __builtin_amdgcn_mfma_f32_16x16x32_bf16(qf1, *(const bf16x8*)&lK[kvr][32 + hi * 8], c, 0, 0, 0);
#pragma unroll
    for (int r = 0; r < 4; ++r) s[g][r] = c[r] * 0.125f;  // HD^-0.5
  }
  if (diag) {
#pragma unroll
    for (int g = 0; g < 4; ++g) {
      int kv_abs = kv0 + g * 16 + rl;
#pragma unroll
      for (int r = 0; r < 4; ++r)
        if (kv_abs > qw + hi * 4 + r) s[g][r] = -1e30f;
    }
  }
  // online softmax (row q spans 16 lanes rl=0..15 -> xor masks 1..8)
  float pm[4];
#pragma unroll
  for (int r = 0; r < 4; ++r)
    pm[r] = fmaxf(fmaxf(s[0][r], s[1][r]), fmaxf(s[2][r], s[3][r]));
#pragma unroll
  for (int mm = 1; mm <= 8; mm <<= 1)
#pragma unroll
    for (int r = 0; r < 4; ++r)
      pm[r] = fmaxf(pm[r], __shfl_xor(pm[r], mm));
  float fac[4], psum[4], p[4][4];
#pragma unroll
  for (int r = 0; r < 4; ++r) {
    float mn = fmaxf(mrow[r], pm[r]);
    fac[r] = __expf(mrow[r] - mn);
    mrow[r] = mn;
    psum[r] = 0.f;
  }
#pragma unroll
  for (int g = 0; g < 4; ++g)
#pragma unroll
    for (int r = 0; r < 4; ++r) {
      p[g][r] = __expf(s[g][r] - mrow[r]);
      psum[r] += p[g][r];
    }
#pragma unroll
  for (int mm = 1; mm <= 8; mm <<= 1)
#pragma unroll
    for (int r = 0; r < 4; ++r)
      psum[r] += __shfl_xor(psum[r], mm);
#pragma unroll
  for (int r = 0; r < 4; ++r) {
    lrow[r] = lrow[r] * fac[r] + psum[r];
#pragma unroll
    for (int n = 0; n < 4; ++n) oacc[n][r] *= fac[r];
  }
  // P -> per-wave LDS (wave-ordered reuse is safe: DS ops complete in order)
#pragma unroll
  for (int g = 0; g < 4; ++g)
#pragma unroll
    for (int r = 0; r < 4; ++r)
      lPw[hi * 4 + r][g * 16 + rl] = f2bf(p[g][r]);
  // PV: oacc[q][d] += P[q][kv] @ V[kv][d]
#pragma unroll
  for (int kk = 0; kk < 2; ++kk) {
    bf16x8 pf = *(const bf16x8*)&lPw[rl][kk * 32 + hi * 8];
#pragma unroll
    for (int n = 0; n < 4; ++n) {
      bf16x8 vf = *(const bf16x8*)&lVt[n * 16 + rl][kk * 32 + hi * 8];
      oacc[n] = __builtin_amdgcn_mfma_f32_16x16x32_bf16(pf, vf, oacc[n], 0, 0, 0);
    }
  }
}

// Balanced causal pairing: block x in [0,16) owns q-tiles xa=x and xb=31-x
// (exactly 33 tile-computes per block); K/V staged once, shared by both.
// Async-stage: next tile's K/V global loads issue before compute, land in
// LDS after the closing barrier (T14). grid (16, B*H), 4 waves.
__global__ __launch_bounds__(256)
void attn_fwd(const u16* Qp, const u16* __restrict__ Kp,
              const u16* __restrict__ Vp, u16* O)
{
  __shared__ u16 lK[64][72];    // K[kv][d]
  __shared__ u16 lVt[64][72];   // V^T[d][kv]
  __shared__ u16 lP[4][16][72]; // per-wave P[q][kv]

  int bh = blockIdx.y;
  int b = bh >> 4, h = bh & 15;
  int xa = blockIdx.x;        // 0..15
  int xb = 31 - xa;           // 16..31
  int t = threadIdx.x, lane = t & 63, w = t >> 6;
  int rl = lane & 15, hi = lane >> 4;
  int qa_w = xa * 64 + w * 16;
  int qb_w = xb * 64 + w * 16;

  const u16* Qb = Qp + ((size_t)b * SEQ) * DIM + h * HD;
  const u16* Kb = Kp + ((size_t)b * SEQ) * DIM + h * HD;
  const u16* Vb = Vp + ((size_t)b * SEQ) * DIM + h * HD;

  // Q fragments for both tiles (hoisted before any in-place O write)
  bf16x8 qa0, qa1, qb0, qb1;
  {
    const u16* qrow = Qb + (size_t)(qa_w + rl) * DIM + hi * 8;
    qa0 = *(const bf16x8*)qrow;
    qa1 = *(const bf16x8*)(qrow + 32);
    qrow = Qb + (size_t)(qb_w + rl) * DIM + hi * 8;
    qb0 = *(const bf16x8*)qrow;
    qb1 = *(const bf16x8*)(qrow + 32);
  }

  f32x4 oA[4] = {}, oB[4] = {};
  float mA[4], lA_[4], mB[4], lB_[4];
#pragma unroll
  for (int r = 0; r < 4; ++r) { mA[r] = mB[r] = -1e30f; lA_[r] = lB_[r] = 0.f; }

  // staging coordinates (constant across tiles)
  int krow = t >> 3;              // K rows krow, krow+32
  int kc8 = (t & 7) * 8;
  int kvv = t & 63;               // V row
  int vd0 = (t >> 6) * 8;         // V d-chunks vd0, vd0+32

  int nt = xb + 1;
  bf16x8 kr0, kr1, vr0, vr1;
  {  // prologue: tile 0
    const u16* Krow = Kb + kc8;
    kr0 = *(const bf16x8*)(Krow + (size_t)krow * DIM);
    kr1 = *(const bf16x8*)(Krow + (size_t)(krow + 32) * DIM);
    const u16* Vrow = Vb + (size_t)kvv * DIM + vd0;
    vr0 = *(const bf16x8*)Vrow;
    vr1 = *(const bf16x8*)(Vrow + 32);
  }

  for (int tile = 0; tile < nt; ++tile) {
    // staged regs -> LDS
    *(bf16x8*)&lK[krow][kc8] = kr0;
    *(bf16x8*)&lK[krow + 32][kc8] = kr1;
#pragma unroll
    for (int j = 0; j < 8; ++j) lVt[vd0 + j][kvv] = (u16)vr0[j];
#pragma unroll
    for (int j = 0; j < 8; ++j) lVt[vd0 + 32 + j][kvv] = (u16)vr1[j];
    __syncthreads();
    // prefetch next tile (latency hides under compute below)
    if (tile + 1 < nt) {
      int kv0n = (tile + 1) * 64;
      const u16* Krow = Kb + (size_t)kv0n * DIM + kc8;
      kr0 = *(const bf16x8*)(Krow + (size_t)krow * DIM);
      kr1 = *(const bf16x8*)(Krow + (size_t)(krow + 32) * DIM);
      const u16* Vrow = Vb + (size_t)(kv0n + kvv) * DIM + vd0;
      vr0 = *(const bf16x8*)Vrow;
      vr1 = *(const bf16x8*)(Vrow + 32);
    }
    int kv0 = tile * 64;
    attn_compute(lK, lVt, lP[w], qb0, qb1, rl, hi, kv0, qb_w, tile == xb, oB, mB, lB_);
    if (tile <= xa)
      attn_compute(lK, lVt, lP[w], qa0, qa1, rl, hi, kv0, qa_w, tile == xa, oA, mA, lA_);
    __syncthreads();
  }

  // epilogue: both q-tiles, O in-place over Q
#pragma unroll
  for (int n = 0; n < 4; ++n) {
    int d = n * 16 + rl;
#pragma unroll
    for (int r = 0; r < 4; ++r) {
      int qq = qa_w + hi * 4 + r;
      O[((size_t)b * SEQ + qq) * DIM + h * HD + d] = f2bf(oA[n][r] / lA_[r]);
      qq = qb_w + hi * 4 + r;
      O[((size_t)b * SEQ + qq) * DIM + h * HD + d] = f2bf(oB[n][r] / lB_[r]);
    }
  }
}

// ------------------------------------------------------------ launch
extern "C" void kernel_launch(void* const* d_in, const int* in_sizes, int n_in,
                              void* d_out, int out_size, void* d_ws, size_t ws_size,
                              hipStream_t stream)
{
  (void)in_sizes; (void)n_in;
  const size_t MB = 1024ull * 1024ull;
  if (ws_size < 32 * MB) {  // diagnostic fallback
    zero_out_k<<<(out_size + 255) / 256, 256, 0, stream>>>((u32*)d_out, out_size);
    return;
  }

  u16* Wt = (u16*)d_ws;                               // 8 MB (4 transposed weights)
  u16* Qp = (u16*)((char*)d_ws + 8 * MB);             // 8 MB (also attention output)
  u16* Kp = (u16*)((char*)d_ws + 16 * MB);            // 8 MB
  u16* Vp = (u16*)((char*)d_ws + 24 * MB);            // 8 MB

  transpose_weights<<<dim3(16, 16, 4), 256, 0, stream>>>(
      (const float*)d_in[3], (const float*)d_in[5], (const float*)d_in[7],
      (const float*)d_in[9], Wt);
  gemm_qkv<<<dim3(32, 8, 3), 256, 0, stream>>>(
      (const float*)d_in[0], (const float*)d_in[1], (const float*)d_in[2], Wt,
      (const float*)d_in[4], (const float*)d_in[6], (const float*)d_in[8], Qp);
  attn_fwd<<<dim3(16, 32), 256, 0, stream>>>(Qp, Kp, Vp, Qp);
  gemm_o<<<dim3(32, 8), 256, 0, stream>>>(Qp, Wt + 3ll * DIM * DIM,
                                          (const float*)d_in[10], (float*)d_out);
}